// Round 8
// baseline (182.839 us; speedup 1.0000x reference)
//
#include <hip/hip_runtime.h>
#include <hip/hip_fp16.h>

#define NN 256
#define VV 25
#define TT 128
#define CIN 64
#define CO 64
#define RR 9
#define HH4 18
#define HH5 6
#define TQ 16
#define NT 8

typedef unsigned int uint;

__device__ __forceinline__ float silu_f(float v) {
  return __fdividef(v, 1.0f + __expf(-v));
}
__device__ __forceinline__ __half2 u2h(uint u) {
  union { uint x; __half2 h; } c; c.x = u; return c.h;
}
__device__ __forceinline__ uint h2u(__half2 h) {
  union { __half2 h; uint x; } c; c.h = h; return c.x;
}

// ---------------------------------------------------------------------------
// k1: per (n,v): coalesced load of 32KB x tile -> HALF LDS transpose;
// x3 = x@W3+b3 -> global rows padded to 32B, layout [n*NT+tq][v][t][8u];
// xm = column sums of x from f32 registers.
// ---------------------------------------------------------------------------
__global__ __launch_bounds__(128) void k1_proj(
    const float* __restrict__ x, const float* __restrict__ W3,
    const float* __restrict__ b3, uint* __restrict__ x3g,
    float* __restrict__ xm) {
  const int blk = blockIdx.x;            // n*V + v
  const int n = blk / VV, v = blk - n * VV;
  const int tid = threadIdx.x;
  __shared__ __align__(16) __half xt[TT * 66];   // 16,896 B
  __shared__ __align__(16) float xmp[2][64];

  const float4* src = (const float4*)(x + (size_t)blk * TT * CIN);
  float4 r[16];
  #pragma unroll
  for (int k = 0; k < 16; ++k) r[k] = src[k * 128 + tid];
  #pragma unroll
  for (int k = 0; k < 16; ++k) {
    const int idx = k * 128 + tid;
    const int t = idx >> 4, c = (idx & 15) * 4;
    *(__half2*)(&xt[t * 66 + c])     = __floats2half2_rn(r[k].x, r[k].y);
    *(__half2*)(&xt[t * 66 + c + 2]) = __floats2half2_rn(r[k].z, r[k].w);
  }
  // column partial sums from f32 registers (mean path stays fp32)
  float4 cs = r[0];
  #pragma unroll
  for (int k = 1; k < 16; ++k) {
    cs.x += r[k].x; cs.y += r[k].y; cs.z += r[k].z; cs.w += r[k].w;
  }
  #pragma unroll
  for (int m = 16; m < 64; m <<= 1) {
    cs.x += __shfl_xor(cs.x, m); cs.y += __shfl_xor(cs.y, m);
    cs.z += __shfl_xor(cs.z, m); cs.w += __shfl_xor(cs.w, m);
  }
  if ((tid & 63) < 16) *(float4*)(&xmp[tid >> 6][(tid & 15) * 4]) = cs;
  __syncthreads();
  if (tid < 64) xm[(size_t)blk * 64 + tid] = xmp[0][tid] + xmp[1][tid];

  // x3 row for t = tid: b32 LDS reads (stride 66 halves -> conflict-free)
  float acc[RR];
  #pragma unroll
  for (int j = 0; j < RR; ++j) acc[j] = b3[j];
  const __half* xrow = xt + tid * 66;
  #pragma unroll 8
  for (int c2 = 0; c2 < 32; ++c2) {
    const __half2 hv = *(const __half2*)(&xrow[c2 * 2]);
    const float x0 = __low2float(hv), x1 = __high2float(hv);
    #pragma unroll
    for (int j = 0; j < RR; ++j) {
      acc[j] = fmaf(x0, W3[(c2 * 2 + 0) * RR + j], acc[j]);
      acc[j] = fmaf(x1, W3[(c2 * 2 + 1) * RR + j], acc[j]);
    }
  }
  uint w0 = h2u(__floats2half2_rn(acc[0], acc[1]));
  uint w1 = h2u(__floats2half2_rn(acc[2], acc[3]));
  uint w2 = h2u(__floats2half2_rn(acc[4], acc[5]));
  uint w3 = h2u(__floats2half2_rn(acc[6], acc[7]));
  uint w4 = h2u(__floats2half2_rn(acc[8], 0.f));
  const int tq = tid >> 4, t = tid & 15;
  uint* dst = x3g + ((((size_t)n * NT + tq) * VV + v) * TQ + t) * 8;
  ((uint4*)dst)[0] = make_uint4(w0, w1, w2, w3);
  ((uint4*)dst)[1] = make_uint4(w4, 0u, 0u, 0u);
}

// ---------------------------------------------------------------------------
// k2: per n: means from xm, rel MLP (9->18->9), + A -> h rows padded to 32B,
// layout [n][u*V+v][8u]
// ---------------------------------------------------------------------------
__global__ __launch_bounds__(128) void k2_h(
    const float* __restrict__ xm, const float* __restrict__ A,
    const float* __restrict__ W1, const float* __restrict__ b1,
    const float* __restrict__ W2, const float* __restrict__ b2,
    const float* __restrict__ W4a, const float* __restrict__ b4a,
    const float* __restrict__ W4b, const float* __restrict__ b4b,
    uint* __restrict__ h2g) {
  const int n = blockIdx.x;
  const int tid = threadIdx.x;
  __shared__ float m1[VV][RR + 1];
  __shared__ float m2[VV][RR + 1];
  const float* xmn = xm + (size_t)n * VV * CIN;
  for (int i = tid; i < 2 * VV * RR; i += 128) {
    const int which = (i >= VV * RR);
    const int idx = which ? i - VV * RR : i;
    const int v = idx / RR, c = idx - v * RR;
    const float* W = which ? W2 : W1;
    const float* b = which ? b2 : b1;
    const float* row = xmn + v * CIN;
    float s = 0.f;
    #pragma unroll
    for (int k = 0; k < CIN; ++k) s = fmaf(row[k], W[k * RR + c], s);
    s = s * (1.0f / TT) + b[c];
    if (which) m2[v][c] = s; else m1[v][c] = s;
  }
  __syncthreads();
  for (int p = tid; p < VV * VV; p += 128) {
    const int u = p / VV, v2 = p - u * VV;
    float rel[RR];
    #pragma unroll
    for (int j = 0; j < RR; ++j) rel[j] = m1[u][j] - m2[v2][j];
    float t1[HH4];
    #pragma unroll
    for (int k = 0; k < HH4; ++k) {
      float s = b4a[k];
      #pragma unroll
      for (int j = 0; j < RR; ++j) s = fmaf(rel[j], W4a[j * HH4 + k], s);
      t1[k] = silu_f(s);
    }
    const float av = A[u * VV + v2];
    float hc[RR];
    #pragma unroll
    for (int j = 0; j < RR; ++j) {
      float s = b4b[j];
      #pragma unroll
      for (int k = 0; k < HH4; ++k) s = fmaf(t1[k], W4b[k * RR + j], s);
      hc[j] = silu_f(s) + av;
    }
    uint* hp = h2g + ((size_t)n * (VV * VV) + p) * 8;
    ((uint4*)hp)[0] = make_uint4(h2u(__floats2half2_rn(hc[0], hc[1])),
                                 h2u(__floats2half2_rn(hc[2], hc[3])),
                                 h2u(__floats2half2_rn(hc[4], hc[5])),
                                 h2u(__floats2half2_rn(hc[6], hc[7])));
    ((uint4*)hp)[1] = make_uint4(h2u(__floats2half2_rn(hc[8], 0.f)), 0u, 0u, 0u);
  }
}

// ---------------------------------------------------------------------------
// k3: per (n,tq): NO staging. C1: each lane owns one (u,t) row; reads x3
// panels (contiguous 512B/instr, 4-way u-broadcast, imm offsets) + h rows
// (imm offsets) straight through L1; agg via hfma2; 9->6 silu -> a5s (f32,
// stride 7, conflict-free). One barrier. C2: broadcast b64 a5 reads,
// 6->64 silu, 1KB-coalesced float4 stores. LDS 11.2 KB.
// ---------------------------------------------------------------------------
__global__ __launch_bounds__(256, 4) void k3_out(
    const uint* __restrict__ x3g, const uint* __restrict__ h2g,
    const float* __restrict__ W5a, const float* __restrict__ b5a,
    const float* __restrict__ W5b, const float* __restrict__ b5b,
    float* __restrict__ out) {
  const int bid = blockIdx.x;           // n*NT + tq
  const int n = bid >> 3, tq = bid & 7;
  const int tid = threadIdx.x;
  __shared__ __align__(16) float a5s[VV * TQ * 7];   // 11,200 B

  const uint* xb = x3g + (size_t)bid * (VV * TQ * 8);

  // C1: 400 rows over 256 threads
  for (int p = tid; p < VV * TQ; p += 256) {
    const int u = p >> 4, t = p & 15;
    const uint* xr = xb + t * 8;                       // + v2*128 (imm-friendly)
    const uint* hr = h2g + ((size_t)n * (VV * VV) + u * VV) * 8;  // + v2*8
    __half2 c0 = u2h(0u), c1 = c0, c2 = c0, c3 = c0, c4 = c0;
    #pragma unroll
    for (int v2 = 0; v2 < VV; ++v2) {
      const uint4 xa = *(const uint4*)(xr + v2 * (TQ * 8));
      const uint  xc = xr[v2 * (TQ * 8) + 4];
      const uint4 ha = *(const uint4*)(hr + v2 * 8);
      const uint  hc = hr[v2 * 8 + 4];
      c0 = __hfma2(u2h(ha.x), u2h(xa.x), c0);
      c1 = __hfma2(u2h(ha.y), u2h(xa.y), c1);
      c2 = __hfma2(u2h(ha.z), u2h(xa.z), c2);
      c3 = __hfma2(u2h(ha.w), u2h(xa.w), c3);
      c4 = __hfma2(u2h(hc),   u2h(xc),   c4);
    }
    float ag[RR];
    ag[0] = __low2float(c0); ag[1] = __high2float(c0);
    ag[2] = __low2float(c1); ag[3] = __high2float(c1);
    ag[4] = __low2float(c2); ag[5] = __high2float(c2);
    ag[6] = __low2float(c3); ag[7] = __high2float(c3);
    ag[8] = __low2float(c4);
    float* d = a5s + p * 7;
    #pragma unroll
    for (int k = 0; k < HH5; ++k) {
      float s = b5a[k];
      #pragma unroll
      for (int j = 0; j < RR; ++j) s = fmaf(ag[j], W5a[j * HH5 + k], s);
      d[k] = silu_f(s);
    }
  }

  // hoist epilogue weights before the barrier
  const int cq = (tid & 15) * 4;
  float4 wb[HH5];
  #pragma unroll
  for (int k = 0; k < HH5; ++k) wb[k] = *(const float4*)(W5b + k * CO + cq);
  const float4 bb = *(const float4*)(b5b + cq);
  __syncthreads();

  // C2: per iter u: 16 lanes/row, rows t2 = tid>>4; stores 4KB/block/iter
  const int t2 = tid >> 4;
  const float* arow = a5s + t2 * 7;                    // + u*112 (imm)
  float* obase = out +
      (((size_t)n * VV) * TT + (size_t)tq * TQ + t2) * CO + cq;
  #pragma unroll 5
  for (int u = 0; u < VV; ++u) {
    const float a0 = arow[u * 112 + 0];
    const float a1 = arow[u * 112 + 1];
    const float a2 = arow[u * 112 + 2];
    const float a3 = arow[u * 112 + 3];
    const float a4 = arow[u * 112 + 4];
    const float a5 = arow[u * 112 + 5];
    float4 y;
    y.x = silu_f(bb.x + a0 * wb[0].x + a1 * wb[1].x + a2 * wb[2].x +
                 a3 * wb[3].x + a4 * wb[4].x + a5 * wb[5].x);
    y.y = silu_f(bb.y + a0 * wb[0].y + a1 * wb[1].y + a2 * wb[2].y +
                 a3 * wb[3].y + a4 * wb[4].y + a5 * wb[5].y);
    y.z = silu_f(bb.z + a0 * wb[0].z + a1 * wb[1].z + a2 * wb[2].z +
                 a3 * wb[3].z + a4 * wb[4].z + a5 * wb[5].z);
    y.w = silu_f(bb.w + a0 * wb[0].w + a1 * wb[1].w + a2 * wb[2].w +
                 a3 * wb[3].w + a4 * wb[4].w + a5 * wb[5].w);
    *(float4*)(obase + (size_t)u * (TT * CO)) = y;
  }
}

extern "C" void kernel_launch(void* const* d_in, const int* in_sizes, int n_in,
                              void* d_out, int out_size, void* d_ws, size_t ws_size,
                              hipStream_t stream) {
  const float* x   = (const float*)d_in[0];
  const float* A   = (const float*)d_in[1];
  const float* W1  = (const float*)d_in[2];
  const float* b1  = (const float*)d_in[3];
  const float* W2  = (const float*)d_in[4];
  const float* b2  = (const float*)d_in[5];
  const float* W3  = (const float*)d_in[6];
  const float* b3  = (const float*)d_in[7];
  const float* W4a = (const float*)d_in[8];
  const float* b4a = (const float*)d_in[9];
  const float* W4b = (const float*)d_in[10];
  const float* b4b = (const float*)d_in[11];
  const float* W5a = (const float*)d_in[12];
  const float* b5a = (const float*)d_in[13];
  const float* W5b = (const float*)d_in[14];
  const float* b5b = (const float*)d_in[15];
  float* out = (float*)d_out;

  char* ws = (char*)d_ws;
  uint*  x3g = (uint*)ws;                        // 256*8*25*16*32 B = 26,214,400
  float* xm  = (float*)(ws + 26214400);          //  1,638,400 B
  uint*  h2g = (uint*)(ws + 26214400 + 1638400); //  5,120,000 B

  hipLaunchKernelGGL(k1_proj, dim3(NN * VV), dim3(128), 0, stream,
                     x, W3, b3, x3g, xm);
  hipLaunchKernelGGL(k2_h, dim3(NN), dim3(128), 0, stream,
                     xm, A, W1, b1, W2, b2, W4a, b4a, W4b, b4b, h2g);
  hipLaunchKernelGGL(k3_out, dim3(NN * NT), dim3(256), 0, stream,
                     x3g, h2g, W5a, b5a, W5b, b5b, out);
}

// Round 9
// 160.338 us; speedup vs baseline: 1.1403x; 1.1403x over previous
//
#include <hip/hip_runtime.h>
#include <hip/hip_fp16.h>

#define NN 256
#define VV 25
#define TT 128
#define CIN 64
#define CO 64
#define RR 9
#define HH4 18
#define HH5 6

typedef unsigned int uint;
typedef unsigned short ushort;
typedef __attribute__((ext_vector_type(8))) short bf16x8;
typedef __attribute__((ext_vector_type(4))) float f32x4;

__device__ __forceinline__ float silu_f(float v) {
  return __fdividef(v, 1.0f + __expf(-v));
}
__device__ __forceinline__ __half2 u2h(uint u) {
  union { uint x; __half2 h; } c; c.x = u; return c.h;
}
__device__ __forceinline__ uint h2u(__half2 h) {
  union { __half2 h; uint x; } c; c.h = h; return c.x;
}
__device__ __forceinline__ ushort f2bf(float f) {
  union { float f; uint u; } c; c.f = f;
  const uint u = c.u + 0x7FFFu + ((c.u >> 16) & 1u);
  return (ushort)(u >> 16);
}

// ---------------------------------------------------------------------------
// k1: per (n,v): coalesced x tile -> fp16 LDS transpose; x3 = x@W3+b3 (f32)
// -> bf16 tile [c][t] in LDS -> coalesced global in layout
// x3g[n][v][th4][c9][t32] (halves, packed as uints). xm = col sums (f32).
// ---------------------------------------------------------------------------
__global__ __launch_bounds__(128) void k1_proj(
    const float* __restrict__ x, const float* __restrict__ W3,
    const float* __restrict__ b3, uint* __restrict__ x3g,
    float* __restrict__ xm) {
  const int blk = blockIdx.x;            // n*V + v
  const int tid = threadIdx.x;
  __shared__ __align__(16) __half xt[TT * 66];     // 16,896 B
  __shared__ __align__(16) float xmp[2][64];
  __shared__ __align__(16) ushort ptile[RR * TT];  // [c][t] bf16, 2304 B

  const float4* src = (const float4*)(x + (size_t)blk * TT * CIN);
  float4 r[16];
  #pragma unroll
  for (int k = 0; k < 16; ++k) r[k] = src[k * 128 + tid];
  #pragma unroll
  for (int k = 0; k < 16; ++k) {
    const int idx = k * 128 + tid;
    const int t = idx >> 4, c = (idx & 15) * 4;
    *(__half2*)(&xt[t * 66 + c])     = __floats2half2_rn(r[k].x, r[k].y);
    *(__half2*)(&xt[t * 66 + c + 2]) = __floats2half2_rn(r[k].z, r[k].w);
  }
  // column partial sums from f32 registers (mean path stays fp32)
  float4 cs = r[0];
  #pragma unroll
  for (int k = 1; k < 16; ++k) {
    cs.x += r[k].x; cs.y += r[k].y; cs.z += r[k].z; cs.w += r[k].w;
  }
  #pragma unroll
  for (int m = 16; m < 64; m <<= 1) {
    cs.x += __shfl_xor(cs.x, m); cs.y += __shfl_xor(cs.y, m);
    cs.z += __shfl_xor(cs.z, m); cs.w += __shfl_xor(cs.w, m);
  }
  if ((tid & 63) < 16) *(float4*)(&xmp[tid >> 6][(tid & 15) * 4]) = cs;
  __syncthreads();
  if (tid < 64) xm[(size_t)blk * 64 + tid] = xmp[0][tid] + xmp[1][tid];

  // projection for row t = tid (LDS reads, stride 66 halves)
  float acc[RR];
  #pragma unroll
  for (int j = 0; j < RR; ++j) acc[j] = b3[j];
  const __half* xrow = xt + tid * 66;
  #pragma unroll 8
  for (int c2 = 0; c2 < 32; ++c2) {
    const __half2 hv = *(const __half2*)(&xrow[c2 * 2]);
    const float x0 = __low2float(hv), x1 = __high2float(hv);
    #pragma unroll
    for (int j = 0; j < RR; ++j) {
      acc[j] = fmaf(x0, W3[(c2 * 2 + 0) * RR + j], acc[j]);
      acc[j] = fmaf(x1, W3[(c2 * 2 + 1) * RR + j], acc[j]);
    }
  }
  #pragma unroll
  for (int j = 0; j < RR; ++j) ptile[j * TT + tid] = f2bf(acc[j]);
  __syncthreads();

  // coalesced out: uint i of [c][t] -> global [th][c][tp16]
  const uint* tu = (const uint*)ptile;
  uint* dst = x3g + (size_t)blk * 576;
  #pragma unroll
  for (int it = 0; it < 5; ++it) {
    const int i = it * 128 + tid;
    if (i < 576) {
      const int c = i >> 6, tp = i & 63;
      dst[(tp >> 4) * 144 + c * 16 + (tp & 15)] = tu[i];
    }
  }
}

// ---------------------------------------------------------------------------
// k2: per n: means from xm, rel MLP (9->18->9), + A ->
// h2g[n][c9][u32][v32] bf16, zero-padded (u>=25 or v>=25 rows/cols = 0).
// ---------------------------------------------------------------------------
__global__ __launch_bounds__(128) void k2_h(
    const float* __restrict__ xm, const float* __restrict__ A,
    const float* __restrict__ W1, const float* __restrict__ b1,
    const float* __restrict__ W2, const float* __restrict__ b2,
    const float* __restrict__ W4a, const float* __restrict__ b4a,
    const float* __restrict__ W4b, const float* __restrict__ b4b,
    ushort* __restrict__ h2g) {
  const int n = blockIdx.x;
  const int tid = threadIdx.x;
  __shared__ float m1[VV][RR + 1];
  __shared__ float m2[VV][RR + 1];
  const float* xmn = xm + (size_t)n * VV * CIN;
  for (int i = tid; i < 2 * VV * RR; i += 128) {
    const int which = (i >= VV * RR);
    const int idx = which ? i - VV * RR : i;
    const int v = idx / RR, c = idx - v * RR;
    const float* W = which ? W2 : W1;
    const float* b = which ? b2 : b1;
    const float* row = xmn + v * CIN;
    float s = 0.f;
    #pragma unroll
    for (int k = 0; k < CIN; ++k) s = fmaf(row[k], W[k * RR + c], s);
    s = s * (1.0f / TT) + b[c];
    if (which) m2[v][c] = s; else m1[v][c] = s;
  }
  ushort* hb = h2g + (size_t)n * (RR * 1024);
  // zero padding region
  for (int i = tid; i < RR * 1024; i += 128) {
    const int uv = i & 1023;
    if ((uv >> 5) >= VV || (uv & 31) >= VV) hb[i] = 0;
  }
  __syncthreads();
  for (int p = tid; p < VV * VV; p += 128) {
    const int u = p / VV, v2 = p - u * VV;
    float rel[RR];
    #pragma unroll
    for (int j = 0; j < RR; ++j) rel[j] = m1[u][j] - m2[v2][j];
    float t1[HH4];
    #pragma unroll
    for (int k = 0; k < HH4; ++k) {
      float s = b4a[k];
      #pragma unroll
      for (int j = 0; j < RR; ++j) s = fmaf(rel[j], W4a[j * HH4 + k], s);
      t1[k] = silu_f(s);
    }
    const float av = A[u * VV + v2];
    #pragma unroll
    for (int j = 0; j < RR; ++j) {
      float s = b4b[j];
      #pragma unroll
      for (int k = 0; k < HH4; ++k) s = fmaf(t1[k], W4b[k * RR + j], s);
      hb[j * 1024 + u * 32 + v2] = f2bf(silu_f(s) + av);
    }
  }
}

// ---------------------------------------------------------------------------
// k3: per (n, th4): stage x3 slice -> LDS [c][t32][v40] bf16; per wave one
// (mt,nt) 16x16 tile: 9 B-frags (ds_read_b128) + 9 A-frags (global 16B) +
// 9 MFMA f32 acc; per-lane 9->6 silu -> a5s (half2); barrier; coalesced
// 6->64 silu epilogue (float4 stores). LDS 32.6 KB -> 4 blocks/CU.
// ---------------------------------------------------------------------------
__global__ __launch_bounds__(256, 4) void k3_out(
    const uint* __restrict__ x3g, const ushort* __restrict__ h2g,
    const float* __restrict__ W5a, const float* __restrict__ b5a,
    const float* __restrict__ W5b, const float* __restrict__ b5b,
    float* __restrict__ out) {
  const int bid = blockIdx.x;           // n*4 + th
  const int n = bid >> 2, th = bid & 3;
  const int tid = threadIdx.x;
  __shared__ __align__(16) ushort xlds[RR * 32 * 40];  // 23,040 B
  __shared__ __align__(16) uint a5s[VV * 32 * 3];      //  9,600 B

  // stage: x3g[n][v][th][c][tp16] -> xlds[c][t][v]
  const uint* srcu = x3g + (size_t)n * (VV * 576) + th * 144;
  for (int i = tid; i < VV * 144; i += 256) {
    const int v = i / 144, r = i - v * 144;
    const uint w = srcu[v * 576 + r];
    const int c = r >> 4, tpl = r & 15;
    const int base = c * 1280 + (tpl * 2) * 40 + v;
    xlds[base]      = (ushort)(w & 0xffffu);
    xlds[base + 40] = (ushort)(w >> 16);
  }
  // zero K-padding v=25..31
  for (int i = tid; i < RR * 32 * 7; i += 256) {
    const int c = i / 224, r2 = i - c * 224;
    const int t = r2 / 7, v = 25 + (r2 - t * 7);
    xlds[c * 1280 + t * 40 + v] = 0;
  }
  // hoist epilogue weights
  const int cq = (tid & 15) * 4;
  float4 wb[HH5];
  #pragma unroll
  for (int k = 0; k < HH5; ++k) wb[k] = *(const float4*)(W5b + k * CO + cq);
  const float4 bb = *(const float4*)(b5b + cq);
  __syncthreads();

  const int wid = tid >> 6, lane = tid & 63;
  const int nt = wid & 1, mt = wid >> 1;
  const int lr = lane & 15, kb = lane >> 4;
  const int tl = nt * 16 + lr;

  bf16x8 Bf[RR];
  #pragma unroll
  for (int c = 0; c < RR; ++c)
    Bf[c] = *(const bf16x8*)(xlds + c * 1280 + tl * 40 + kb * 8);

  const ushort* hbase = h2g + (size_t)n * (RR * 1024) + (mt * 16 + lr) * 32 + kb * 8;
  f32x4 acc[RR];
  #pragma unroll
  for (int c = 0; c < RR; ++c) {
    const bf16x8 Af = *(const bf16x8*)(hbase + c * 1024);
    f32x4 z = {0.f, 0.f, 0.f, 0.f};
    acc[c] = __builtin_amdgcn_mfma_f32_16x16x32_bf16(Af, Bf[c], z, 0, 0, 0);
  }

  // per-lane rows: u = mt*16 + kb*4 + j, col t = tl
  #pragma unroll
  for (int j = 0; j < 4; ++j) {
    const int u = mt * 16 + kb * 4 + j;
    if (u < VV) {
      float a5v[HH5];
      #pragma unroll
      for (int k = 0; k < HH5; ++k) {
        float s = b5a[k];
        #pragma unroll
        for (int c = 0; c < RR; ++c) s = fmaf(acc[c][j], W5a[c * HH5 + k], s);
        a5v[k] = silu_f(s);
      }
      uint* d = a5s + (u * 32 + tl) * 3;
      d[0] = h2u(__floats2half2_rn(a5v[0], a5v[1]));
      d[1] = h2u(__floats2half2_rn(a5v[2], a5v[3]));
      d[2] = h2u(__floats2half2_rn(a5v[4], a5v[5]));
    }
  }
  __syncthreads();

  // C2: 16 lanes per row, 4 channels each; 1KB-coalesced stores
  for (int it = 0; it < 50; ++it) {
    const int q = it * 16 + (tid >> 4);
    const int u = q >> 5, tl2 = q & 31;
    const __half2 p01 = u2h(a5s[q * 3 + 0]);
    const __half2 p23 = u2h(a5s[q * 3 + 1]);
    const __half2 p45 = u2h(a5s[q * 3 + 2]);
    const float a0 = __low2float(p01), a1 = __high2float(p01);
    const float a2 = __low2float(p23), a3 = __high2float(p23);
    const float a4 = __low2float(p45), a5 = __high2float(p45);
    float4 y;
    y.x = silu_f(bb.x + a0 * wb[0].x + a1 * wb[1].x + a2 * wb[2].x +
                 a3 * wb[3].x + a4 * wb[4].x + a5 * wb[5].x);
    y.y = silu_f(bb.y + a0 * wb[0].y + a1 * wb[1].y + a2 * wb[2].y +
                 a3 * wb[3].y + a4 * wb[4].y + a5 * wb[5].y);
    y.z = silu_f(bb.z + a0 * wb[0].z + a1 * wb[1].z + a2 * wb[2].z +
                 a3 * wb[3].z + a4 * wb[4].z + a5 * wb[5].z);
    y.w = silu_f(bb.w + a0 * wb[0].w + a1 * wb[1].w + a2 * wb[2].w +
                 a3 * wb[3].w + a4 * wb[4].w + a5 * wb[5].w);
    float* orow = out +
        (((size_t)(n * VV + u)) * TT + th * 32 + tl2) * CO + cq;
    *(float4*)orow = y;
  }
}

extern "C" void kernel_launch(void* const* d_in, const int* in_sizes, int n_in,
                              void* d_out, int out_size, void* d_ws, size_t ws_size,
                              hipStream_t stream) {
  const float* x   = (const float*)d_in[0];
  const float* A   = (const float*)d_in[1];
  const float* W1  = (const float*)d_in[2];
  const float* b1  = (const float*)d_in[3];
  const float* W2  = (const float*)d_in[4];
  const float* b2  = (const float*)d_in[5];
  const float* W3  = (const float*)d_in[6];
  const float* b3  = (const float*)d_in[7];
  const float* W4a = (const float*)d_in[8];
  const float* b4a = (const float*)d_in[9];
  const float* W4b = (const float*)d_in[10];
  const float* b4b = (const float*)d_in[11];
  const float* W5a = (const float*)d_in[12];
  const float* b5a = (const float*)d_in[13];
  const float* W5b = (const float*)d_in[14];
  const float* b5b = (const float*)d_in[15];
  float* out = (float*)d_out;

  char* ws = (char*)d_ws;
  uint*   x3g = (uint*)ws;                          // 6400*576*4 = 14,745,600 B
  float*  xm  = (float*)(ws + 14745600);            //  1,638,400 B
  ushort* h2g = (ushort*)(ws + 16384000);           //  4,718,592 B

  hipLaunchKernelGGL(k1_proj, dim3(NN * VV), dim3(128), 0, stream,
                     x, W3, b3, x3g, xm);
  hipLaunchKernelGGL(k2_h, dim3(NN), dim3(128), 0, stream,
                     xm, A, W1, b1, W2, b2, W4a, b4a, W4b, b4b, h2g);
  hipLaunchKernelGGL(k3_out, dim3(NN * 4), dim3(256), 0, stream,
                     x3g, h2g, W5a, b5a, W5b, b5b, out);
}